// Round 10
// baseline (10217.488 us; speedup 1.0000x reference)
//
#include <hip/hip_runtime.h>
#include <hip/hip_bf16.h>
#include <math.h>

#define NB 32
#define NN 1500
#define NE 24000
#define HIST_L 24
#define PRED_L 24
#define FDIM 31
#define INUM 32
#define HID 256
#define ROWS (NB*NN)   // 48000
#define XGW 320        // xt(32) + g(256) + zero-pad(32)
#define CTXW 96        // xt | T1 | T2
#define NRB 375        // row blocks

typedef float f32x4 __attribute__((ext_vector_type(4)));
typedef short bf16x8 __attribute__((ext_vector_type(8)));
typedef short bf16x4 __attribute__((ext_vector_type(4)));

__device__ __forceinline__ float sigf(float x){ return 1.0f/(1.0f+expf(-x)); }
__device__ __forceinline__ unsigned short f2b(float f){
    __hip_bfloat16 h = __float2bfloat16(f);
    return __builtin_bit_cast(unsigned short, h);
}
__device__ __forceinline__ float b2f(unsigned short u){
    unsigned int x = ((unsigned int)u) << 16;
    return __builtin_bit_cast(float, x);
}

#define AS1 __attribute__((address_space(1)))
#define AS3 __attribute__((address_space(3)))
__device__ __forceinline__ void gload16(const void* g, void* l){
    __builtin_amdgcn_global_load_lds((const AS1 unsigned int*)g, (AS3 unsigned int*)l, 16, 0, 0);
}

// ---------------- precompute: degrees, CSR by dst (deterministic) ----------------
__global__ void k_count(const int* __restrict__ ei, int* deg, int* cnt){
    int e = blockIdx.x*blockDim.x + threadIdx.x;
    if (e < NE){ atomicAdd(&deg[ei[e]], 1); atomicAdd(&cnt[ei[NE+e]], 1); }
}

__global__ void k_prefix(const int* __restrict__ cnt, int* __restrict__ coff){
    int lane = threadIdx.x;            // 64 threads, 1 wave
    const int CH = (NN + 63)/64;       // 24
    int s = 0;
    for (int i=0;i<CH;i++){ int n = lane*CH+i; if (n<NN) s += cnt[n]; }
    int incl = s;
    for (int off=1; off<64; off<<=1){ int v = __shfl_up(incl, off); if (lane>=off) incl += v; }
    int run = incl - s;                // exclusive
    for (int i=0;i<CH;i++){ int n = lane*CH+i; if (n<NN){ coff[n] = run; run += cnt[n]; } }
    if (lane==63) coff[NN] = run;
}

// wave-parallel order-preserving CSR fill: one wave per node, ballot-ranked.
__global__ __launch_bounds__(256) void k_fillw(
    const int* __restrict__ ei, const int* __restrict__ deg,
    const int* __restrict__ coff, int* __restrict__ csrc, float* __restrict__ cw){
    int n = blockIdx.x*4 + (threadIdx.x >> 6);
    if (n >= NN) return;
    int lane = threadIdx.x & 63;
    int dn = deg[n];
    float disn = dn>0 ? rsqrtf((float)dn) : 0.0f;
    int pos = coff[n];
    for (int base=0; base<NE; base+=64){
        int e = base + lane;
        int d = ei[NE+e];
        bool m = (d == n);
        unsigned long long mask = __ballot(m);
        if (m){
            int rank = __popcll(mask & ((1ull<<lane)-1ull));
            int s = ei[e];
            int ds = deg[s];
            float diss = ds>0 ? rsqrtf((float)ds) : 0.0f;
            csrc[pos+rank] = s;
            cw[pos+rank] = -(diss*disn);
        }
        pos += __popcll(mask);
    }
}

// ---------------- one-time weight conversions ----------------
__global__ void k_f2b(const float* __restrict__ src, unsigned short* __restrict__ dst, int n){
    int i = blockIdx.x*256 + threadIdx.x;
    if (i < n) dst[i] = f2b(src[i]);
}
// Wih [768][288] -> [768][320] bf16, zero pad
__global__ void k_wihr(const float* __restrict__ W, unsigned short* __restrict__ Wr){
    int i = blockIdx.x*256 + threadIdx.x;
    if (i < 768*XGW){
        int r = i/XGW, c = i - r*XGW;
        Wr[i] = (c < INUM+HID) ? f2b(W[(size_t)r*(INUM+HID) + c]) : (unsigned short)0;
    }
}
// Wc flat [96][256] -> Wctr [256][96] bf16
__global__ void k_wctr(const float* __restrict__ Wc, unsigned short* __restrict__ W){
    int i = blockIdx.x*256 + threadIdx.x;
    if (i < 256*96){
        int j = i/96, k = i - j*96;
        W[i] = f2b(Wc[(size_t)k*256 + j]);
    }
}

// ---------------- per-step small kernels ----------------
__global__ void k_build_xt(const float* __restrict__ ch0, int bstride, int choff, int addb,
                           const float* __restrict__ bfc,
                           const float* __restrict__ feats, int tf,
                           float* __restrict__ xt, unsigned short* __restrict__ ctx,
                           unsigned short* __restrict__ xg){
    int idx = blockIdx.x*blockDim.x + threadIdx.x;
    if (idx >= ROWS*INUM) return;
    int r = idx >> 5, c = idx & 31;
    int b = r / NN, n = r - b*NN;
    float v;
    if (c == 0){ v = ch0[b*bstride + choff + n]; if (addb) v += bfc[0]; }
    else         v = feats[((size_t)(b*(HIST_L+PRED_L) + tf)*NN + n)*FDIM + (c-1)];
    xt[idx] = v;
    unsigned short bv = f2b(v);
    ctx[(size_t)r*CTXW + c] = bv;
    xg[(size_t)r*XGW + c] = bv;
}

// float4-vectorized Lx: res = scale*L_hat(vin) - (sub?sub:0); fp32 out nullable; bf16 into ctx col slice
__global__ void k_lx4(const float* __restrict__ vin, const int* __restrict__ coff,
                      const int* __restrict__ csrc, const float* __restrict__ cw,
                      const float* __restrict__ sub, float scale,
                      float* __restrict__ vout, unsigned short* __restrict__ ctxo){
    int idx = blockIdx.x*256 + threadIdx.x;
    if (idx >= ROWS*8) return;
    int r = idx >> 3, l8 = idx & 7;
    int b = r / NN, n = r - b*NN;
    int j0 = coff[n], j1 = coff[n+1];
    const float4* vb = (const float4*)(vin + (size_t)b*NN*INUM);
    float ax=0.f, ay=0.f, az=0.f, aw=0.f;
    for (int j=j0;j<j1;j++){
        float w = cw[j];
        float4 v = vb[csrc[j]*8 + l8];
        ax += w*v.x; ay += w*v.y; az += w*v.z; aw += w*v.w;
    }
    ax *= scale; ay *= scale; az *= scale; aw *= scale;
    if (sub){
        float4 s = ((const float4*)sub)[idx];
        ax -= s.x; ay -= s.y; az -= s.z; aw -= s.w;
    }
    if (vout){
        float4 o; o.x=ax; o.y=ay; o.z=az; o.w=aw;
        ((float4*)vout)[idx] = o;
    }
    bf16x4 ob;
    ob[0]=(short)f2b(ax); ob[1]=(short)f2b(ay); ob[2]=(short)f2b(az); ob[3]=(short)f2b(aw);
    *(bf16x4*)&ctxo[(size_t)r*CTXW + l8*4] = ob;
}

// ---------------- Cheb GEMM full-N: xg[:,32:288] = sigmoid(ctx @ Wctr^T + bc) ----------------
__global__ __launch_bounds__(256,2) void k_cheb3(
    const unsigned short* __restrict__ ctx, const unsigned short* __restrict__ Wctr,
    const float* __restrict__ bc, unsigned short* __restrict__ xg)
{
    __shared__ __align__(16) unsigned short A[128*104];   // 26.0 KB
    __shared__ __align__(16) unsigned short B[256*104];   // 52.0 KB
    const int tid = threadIdx.x, wid = tid>>6, lane = tid&63;
    const int wm = wid>>1, wn = wid&1;
    const int r0 = blockIdx.x*128;
    const int l15 = lane&15, lhi = lane>>4;

    #pragma unroll
    for (int i=0;i<6;i++){
        int idx = tid + i*256;            // 1536 chunks
        int row = idx/12, c = idx - row*12;
        *(int4*)&A[row*104 + c*8] = *(const int4*)&ctx[(size_t)(r0+row)*96 + c*8];
    }
    #pragma unroll
    for (int i=0;i<12;i++){
        int idx = tid + i*256;            // 3072 chunks
        int row = idx/12, c = idx - row*12;
        *(int4*)&B[row*104 + c*8] = *(const int4*)&Wctr[(size_t)row*96 + c*8];
    }
    __syncthreads();

    f32x4 acc[4][8] = {};
    #pragma unroll
    for (int ks=0; ks<3; ks++){
        bf16x8 a[4];
        #pragma unroll
        for (int mi=0;mi<4;mi++)
            a[mi] = *(const bf16x8*)&A[(wm*64+mi*16+l15)*104 + ks*32 + lhi*8];
        #pragma unroll
        for (int ni=0;ni<8;ni++){
            bf16x8 b = *(const bf16x8*)&B[(wn*128+ni*16+l15)*104 + ks*32 + lhi*8];
            #pragma unroll
            for (int mi=0;mi<4;mi++)
                acc[mi][ni] = __builtin_amdgcn_mfma_f32_16x16x32_bf16(a[mi], b, acc[mi][ni],0,0,0);
        }
    }
    #pragma unroll
    for (int ni=0;ni<8;ni++){
        int col = wn*128 + ni*16 + l15;
        float bcv = bc[col];
        #pragma unroll
        for (int mi=0;mi<4;mi++){
            #pragma unroll
            for (int v=0;v<4;v++){
                size_t row = r0 + wm*64 + mi*16 + lhi*4 + v;
                xg[row*XGW + 32 + col] = f2b(sigf(acc[mi][ni][v] + bcv));
            }
        }
    }
}

// ---------------- GRU tile compute (BK=32) ----------------
__device__ __forceinline__ void gtile(const unsigned short* Ap, const unsigned short* Bp,
    int wm, int wn, int l15, int q,
    f32x4 (&ar)[4][2], f32x4 (&az)[4][2], f32x4 (&a3)[4][2])
{
    bf16x8 a[4];
    #pragma unroll
    for (int mi=0;mi<4;mi++)
        a[mi] = *(const bf16x8*)&Ap[(wm*64 + mi*16 + l15)*32 + q];
    #pragma unroll
    for (int slab=0; slab<3; slab++){
        bf16x8 b0 = *(const bf16x8*)&Bp[(slab*64 + wn*32 + l15)*32 + q];
        bf16x8 b1 = *(const bf16x8*)&Bp[(slab*64 + wn*32 + 16 + l15)*32 + q];
        f32x4 (&acc)[4][2] = (slab==0)?ar:((slab==1)?az:a3);
        #pragma unroll
        for (int mi=0;mi<4;mi++){
            acc[mi][0] = __builtin_amdgcn_mfma_f32_16x16x32_bf16(a[mi], b0, acc[mi][0],0,0,0);
            acc[mi][1] = __builtin_amdgcn_mfma_f32_16x16x32_bf16(a[mi], b1, acc[mi][1],0,0,0);
        }
    }
}

// fused GRU cell: BK=32 dbuf (40KB LDS -> 4 blocks/CU), XCD-aligned grid, fused FC (decoder)
__global__ __launch_bounds__(256,4) void k_gru5(
    const unsigned short* __restrict__ xg, const unsigned short* __restrict__ hbin,
    const unsigned short* __restrict__ Wihr, const unsigned short* __restrict__ Whhr,
    const float* __restrict__ bih, const float* __restrict__ bhh,
    unsigned short* __restrict__ hbout,
    const float* __restrict__ Wfc, float* __restrict__ outp, int p)
{
    __shared__ __align__(16) unsigned short As[2][128*32];  // 2 x 8KB
    __shared__ __align__(16) unsigned short Bs[2][192*32];  // 2 x 12KB
    // XCD-aligned bijective swizzle: the 4 col-blocks of row-block R share id%8
    const int bi = blockIdx.x;
    const int xc = bi & 7, t = bi >> 3;
    const int R = xc + 8*(t>>2);
    if (R >= NRB) return;
    const int r0 = R*128, j0 = (t&3)*64;

    const int tid = threadIdx.x, wid = tid>>6, lane = tid&63;
    const int wm = wid>>1, wn = wid&1;
    const int l15 = lane&15, lhi = lane>>4;
    const int cl = lane>>2;
    const int swz = ((lane&3) ^ (cl&3))*16;
    const int q = (lhi ^ (l15&3))*8;

    f32x4 ar[4][2]={}, az[4][2]={}, ain[4][2]={}, ahn[4][2]={};

    auto stageA = [&](int ks, int bs){
        char* Ld = (char*)&As[bs][0] + wid*2048;
        const char* src; size_t stride;
        if (ks < 9){ src = (const char*)xg   + (size_t)r0*640 + (size_t)ks*64;     stride = 640; }
        else       { src = (const char*)hbin + (size_t)r0*512 + (size_t)(ks-9)*64; stride = 512; }
        #pragma unroll
        for (int i=0;i<2;i++){
            int row = wid*32 + i*16 + cl;
            gload16(src + (size_t)row*stride + swz, Ld + i*1024);
        }
    };
    auto stageB = [&](int ks, int bs){
        char* Ld = (char*)&Bs[bs][0] + wid*3072;
        const char* src; size_t stride; int kb;
        if (ks < 9){ src = (const char*)Wihr; stride = 640; kb = ks; }
        else       { src = (const char*)Whhr; stride = 512; kb = ks-9; }
        #pragma unroll
        for (int i=0;i<3;i++){
            int j = wid*3 + i;
            int wrow = (j>>2)*256 + j0 + (j&3)*16 + cl;
            gload16(src + (size_t)wrow*stride + (size_t)kb*64 + swz, Ld + i*1024);
        }
    };

    stageA(0,0); stageB(0,0);
    __syncthreads();
    for (int ks=0; ks<9; ks++){
        int cur = ks&1;
        { stageA(ks+1, cur^1); stageB(ks+1, cur^1); }
        gtile(&As[cur][0], &Bs[cur][0], wm, wn, l15, q, ar, az, ain);
        __syncthreads();
    }
    for (int ks=9; ks<17; ks++){
        int cur = ks&1;
        if (ks<16){ stageA(ks+1, cur^1); stageB(ks+1, cur^1); }
        gtile(&As[cur][0], &Bs[cur][0], wm, wn, l15, q, ar, az, ahn);
        __syncthreads();
    }
    // ---- fused gate epilogue (bf16 state) + optional fused FC partial ----
    float fcp[4][4] = {};
    float wf[2];
    if (p >= 0){
        wf[0] = Wfc[j0 + wn*32 + l15];
        wf[1] = Wfc[j0 + wn*32 + 16 + l15];
    }
    #pragma unroll
    for (int ni=0; ni<2; ni++){
        int col = j0 + wn*32 + ni*16 + l15;
        float br = bih[col]       + bhh[col];
        float bz = bih[col+HID]   + bhh[col+HID];
        float bi = bih[col+2*HID];
        float bh = bhh[col+2*HID];
        #pragma unroll
        for (int mi=0; mi<4; mi++){
            #pragma unroll
            for (int v=0; v<4; v++){
                size_t row = r0 + wm*64 + mi*16 + lhi*4 + v;
                float r  = sigf(ar[mi][ni][v] + br);
                float z  = sigf(az[mi][ni][v] + bz);
                float nn = tanhf(ain[mi][ni][v] + bi + r*(ahn[mi][ni][v] + bh));
                float ho = b2f(hbin[row*HID + col]);
                float hv = (1.f - z)*nn + z*ho;
                hbout[row*HID + col] = f2b(hv);
                if (p >= 0) fcp[mi][v] += hv * wf[ni];
            }
        }
    }
    if (p >= 0){
        #pragma unroll
        for (int mi=0; mi<4; mi++){
            #pragma unroll
            for (int v=0; v<4; v++){
                float s = fcp[mi][v];
                s += __shfl_xor(s, 1);
                s += __shfl_xor(s, 2);
                s += __shfl_xor(s, 4);
                s += __shfl_xor(s, 8);
                if (l15 == 0){
                    int row = r0 + wm*64 + mi*16 + lhi*4 + v;
                    int bb = row / NN, n = row - bb*NN;
                    atomicAdd(&outp[(size_t)(bb*PRED_L + p)*NN + n], s);
                }
            }
        }
    }
}

extern "C" void kernel_launch(void* const* d_in, const int* in_sizes, int n_in,
                              void* d_out, int out_size, void* d_ws, size_t ws_size,
                              hipStream_t stream){
    const float* x_hist = (const float*)d_in[0];
    const float* feats  = (const float*)d_in[1];
    const int*   ei     = (const int*)d_in[2];
    const float* Wc     = (const float*)d_in[3];
    const float* bc     = (const float*)d_in[4];
    const float* Wih    = (const float*)d_in[5];
    const float* bih    = (const float*)d_in[6];
    const float* Whh    = (const float*)d_in[7];
    const float* bhh    = (const float*)d_in[8];
    const float* Wfc    = (const float*)d_in[9];
    const float* bfc    = (const float*)d_in[10];
    float* out = (float*)d_out;

    char* wsp = (char*)d_ws;
    size_t off = 0;
    auto alloc = [&](size_t bytes)->char*{
        char* p = wsp + off; off = (off + bytes + 255) & ~(size_t)255; return p;
    };
    int*   deg  = (int*)  alloc(NN*4);
    int*   cnt  = (int*)  alloc(NN*4);
    int*   coff = (int*)  alloc((NN+1)*4);
    int*   csrc = (int*)  alloc(NE*4);
    float* cw   = (float*)alloc(NE*4);
    float* xt   = (float*)alloc((size_t)ROWS*INUM*4);
    float* T1   = (float*)alloc((size_t)ROWS*INUM*4);
    unsigned short* ctx = (unsigned short*)alloc((size_t)ROWS*CTXW*2);
    unsigned short* xgb = (unsigned short*)alloc((size_t)ROWS*XGW*2);
    unsigned short* hbA = (unsigned short*)alloc((size_t)ROWS*HID*2);
    unsigned short* hbB = (unsigned short*)alloc((size_t)ROWS*HID*2);
    unsigned short* Wihr = (unsigned short*)alloc((size_t)768*XGW*2);
    unsigned short* Whhr = (unsigned short*)alloc((size_t)768*HID*2);
    unsigned short* Wctr = (unsigned short*)alloc((size_t)256*CTXW*2);

    hipMemsetAsync(deg, 0, NN*4, stream);
    hipMemsetAsync(cnt, 0, NN*4, stream);
    hipMemsetAsync(hbA, 0, (size_t)ROWS*HID*2, stream);
    hipMemsetAsync(xgb, 0, (size_t)ROWS*XGW*2, stream);   // zero pad cols persist
    hipMemsetAsync(out, 0, (size_t)out_size*4, stream);   // fc atomics accumulate into out

    k_count<<<(NE+255)/256,256,0,stream>>>(ei, deg, cnt);
    k_prefix<<<1,64,0,stream>>>(cnt, coff);
    k_fillw<<<NRB,256,0,stream>>>(ei, deg, coff, csrc, cw);

    { int n = 768*XGW; k_wihr<<<(n+255)/256,256,0,stream>>>(Wih, Wihr); }
    { int n = 768*HID; k_f2b<<<(n+255)/256,256,0,stream>>>(Whh, Whhr, n); }
    { int n = 256*CTXW; k_wctr<<<(n+255)/256,256,0,stream>>>(Wc, Wctr); }

    unsigned short* hbin = hbA; unsigned short* hbout = hbB;
    const int gruGrid = 1504;     // 8 XCD classes; (R,c) swizzled in-kernel
    const int chebGrid = NRB;
    const int NT  = (ROWS*INUM+255)/256;
    const int NT8 = (ROWS*8+255)/256;

    auto step = [&](const float* ch0, int bstride, int choff, int addb, int tf, int p){
        k_build_xt<<<NT,256,0,stream>>>(ch0, bstride, choff, addb, bfc, feats, tf, xt, ctx, xgb);
        k_lx4<<<NT8,256,0,stream>>>(xt, coff, csrc, cw, nullptr, 1.f, T1, ctx + 32);
        k_lx4<<<NT8,256,0,stream>>>(T1, coff, csrc, cw, xt, 2.f, nullptr, ctx + 64);
        k_cheb3<<<chebGrid,256,0,stream>>>(ctx, Wctr, bc, xgb);
        k_gru5<<<gruGrid,256,0,stream>>>(xgb, hbin, Wihr, Whhr, bih, bhh, hbout, Wfc, out, p);
        unsigned short* t = hbin; hbin = hbout; hbout = t;
    };

    for (int t=0;t<HIST_L-1;t++)
        step(x_hist, HIST_L*NN, t*NN, 0, t+1, -1);
    for (int p=0;p<PRED_L;p++){
        if (p==0) step(x_hist, HIST_L*NN, (HIST_L-1)*NN, 0, HIST_L+p, p);
        else      step(out, PRED_L*NN, (p-1)*NN, 1, HIST_L+p, p);
    }
}

// Round 11
// 6873.424 us; speedup vs baseline: 1.4865x; 1.4865x over previous
//
#include <hip/hip_runtime.h>
#include <hip/hip_bf16.h>
#include <math.h>

#define NB 32
#define NN 1500
#define NE 24000
#define HIST_L 24
#define PRED_L 24
#define FDIM 31
#define INUM 32
#define HID 256
#define ROWS (NB*NN)   // 48000
#define XGW 320        // xt(32) + g(256) + zero-pad(32)
#define CTXW 96        // xt | T1 | T2
#define NRB 375        // row blocks

typedef float f32x4 __attribute__((ext_vector_type(4)));
typedef short bf16x8 __attribute__((ext_vector_type(8)));
typedef short bf16x4 __attribute__((ext_vector_type(4)));

__device__ __forceinline__ float sigf(float x){ return 1.0f/(1.0f+expf(-x)); }
__device__ __forceinline__ unsigned short f2b(float f){
    __hip_bfloat16 h = __float2bfloat16(f);
    return __builtin_bit_cast(unsigned short, h);
}
__device__ __forceinline__ float b2f(unsigned short u){
    unsigned int x = ((unsigned int)u) << 16;
    return __builtin_bit_cast(float, x);
}

#define AS1 __attribute__((address_space(1)))
#define AS3 __attribute__((address_space(3)))
__device__ __forceinline__ void gload16(const void* g, void* l){
    __builtin_amdgcn_global_load_lds((const AS1 unsigned int*)g, (AS3 unsigned int*)l, 16, 0, 0);
}

// ---------------- precompute: degrees, CSR by dst (deterministic) ----------------
__global__ void k_count(const int* __restrict__ ei, int* deg, int* cnt){
    int e = blockIdx.x*blockDim.x + threadIdx.x;
    if (e < NE){ atomicAdd(&deg[ei[e]], 1); atomicAdd(&cnt[ei[NE+e]], 1); }
}

__global__ void k_prefix(const int* __restrict__ cnt, int* __restrict__ coff){
    int lane = threadIdx.x;            // 64 threads, 1 wave
    const int CH = (NN + 63)/64;       // 24
    int s = 0;
    for (int i=0;i<CH;i++){ int n = lane*CH+i; if (n<NN) s += cnt[n]; }
    int incl = s;
    for (int off=1; off<64; off<<=1){ int v = __shfl_up(incl, off); if (lane>=off) incl += v; }
    int run = incl - s;                // exclusive
    for (int i=0;i<CH;i++){ int n = lane*CH+i; if (n<NN){ coff[n] = run; run += cnt[n]; } }
    if (lane==63) coff[NN] = run;
}

// wave-parallel order-preserving CSR fill: one wave per node, ballot-ranked.
__global__ __launch_bounds__(256) void k_fillw(
    const int* __restrict__ ei, const int* __restrict__ deg,
    const int* __restrict__ coff, int* __restrict__ csrc, float* __restrict__ cw){
    int n = blockIdx.x*4 + (threadIdx.x >> 6);
    if (n >= NN) return;
    int lane = threadIdx.x & 63;
    int dn = deg[n];
    float disn = dn>0 ? rsqrtf((float)dn) : 0.0f;
    int pos = coff[n];
    for (int base=0; base<NE; base+=64){
        int e = base + lane;
        int d = ei[NE+e];
        bool m = (d == n);
        unsigned long long mask = __ballot(m);
        if (m){
            int rank = __popcll(mask & ((1ull<<lane)-1ull));
            int s = ei[e];
            int ds = deg[s];
            float diss = ds>0 ? rsqrtf((float)ds) : 0.0f;
            csrc[pos+rank] = s;
            cw[pos+rank] = -(diss*disn);
        }
        pos += __popcll(mask);
    }
}

// ---------------- one-time weight conversions ----------------
__global__ void k_f2b(const float* __restrict__ src, unsigned short* __restrict__ dst, int n){
    int i = blockIdx.x*256 + threadIdx.x;
    if (i < n) dst[i] = f2b(src[i]);
}
__global__ void k_wihr(const float* __restrict__ W, unsigned short* __restrict__ Wr){
    int i = blockIdx.x*256 + threadIdx.x;
    if (i < 768*XGW){
        int r = i/XGW, c = i - r*XGW;
        Wr[i] = (c < INUM+HID) ? f2b(W[(size_t)r*(INUM+HID) + c]) : (unsigned short)0;
    }
}
__global__ void k_wctr(const float* __restrict__ Wc, unsigned short* __restrict__ W){
    int i = blockIdx.x*256 + threadIdx.x;
    if (i < 256*96){
        int j = i/96, k = i - j*96;
        W[i] = f2b(Wc[(size_t)k*256 + j]);
    }
}

// ---------------- batched per-step small kernels (slice s = blockIdx.y) ----------------
__global__ void k_build(const float* __restrict__ ch0, int bstride, int choff0, int chstep, int addb,
                        const float* __restrict__ bfc,
                        const float* __restrict__ feats, int tf0,
                        float* __restrict__ xt, unsigned short* __restrict__ ctx,
                        unsigned short* __restrict__ xg){
    int s = blockIdx.y;
    int idx = blockIdx.x*blockDim.x + threadIdx.x;
    if (idx >= ROWS*INUM) return;
    xt  += (size_t)s*ROWS*INUM;
    ctx += (size_t)s*ROWS*CTXW;
    xg  += (size_t)s*ROWS*XGW;
    int choff = choff0 + s*chstep;
    int tf = tf0 + s;
    int r = idx >> 5, c = idx & 31;
    int b = r / NN, n = r - b*NN;
    float v;
    if (c == 0){ v = ch0[b*bstride + choff + n]; if (addb) v += bfc[0]; }
    else         v = feats[((size_t)(b*(HIST_L+PRED_L) + tf)*NN + n)*FDIM + (c-1)];
    xt[idx] = v;
    unsigned short bv = f2b(v);
    ctx[(size_t)r*CTXW + c] = bv;
    xg[(size_t)r*XGW + c] = bv;
}

// batched Lx: res = scale*L_hat(vin) - (sub?sub:0); fp32 out nullable; bf16 into ctx col slice
__global__ void k_lx4(const float* __restrict__ vin, const int* __restrict__ coff,
                      const int* __restrict__ csrc, const float* __restrict__ cw,
                      const float* __restrict__ sub, float scale,
                      float* __restrict__ vout, unsigned short* __restrict__ ctxo){
    int s = blockIdx.y;
    int idx = blockIdx.x*256 + threadIdx.x;
    if (idx >= ROWS*8) return;
    vin += (size_t)s*ROWS*INUM;
    if (sub)  sub  += (size_t)s*ROWS*INUM;
    if (vout) vout += (size_t)s*ROWS*INUM;
    ctxo += (size_t)s*ROWS*CTXW;
    int r = idx >> 3, l8 = idx & 7;
    int b = r / NN, n = r - b*NN;
    int j0 = coff[n], j1 = coff[n+1];
    const float4* vb = (const float4*)(vin + (size_t)b*NN*INUM);
    float ax=0.f, ay=0.f, az=0.f, aw=0.f;
    for (int j=j0;j<j1;j++){
        float w = cw[j];
        float4 v = vb[csrc[j]*8 + l8];
        ax += w*v.x; ay += w*v.y; az += w*v.z; aw += w*v.w;
    }
    ax *= scale; ay *= scale; az *= scale; aw *= scale;
    if (sub){
        float4 sv = ((const float4*)sub)[idx];
        ax -= sv.x; ay -= sv.y; az -= sv.z; aw -= sv.w;
    }
    if (vout){
        float4 o; o.x=ax; o.y=ay; o.z=az; o.w=aw;
        ((float4*)vout)[idx] = o;
    }
    bf16x4 ob;
    ob[0]=(short)f2b(ax); ob[1]=(short)f2b(ay); ob[2]=(short)f2b(az); ob[3]=(short)f2b(aw);
    *(bf16x4*)&ctxo[(size_t)r*CTXW + l8*4] = ob;
}

// ---------------- batched Cheb GEMM: xg[:,32:288] = sigmoid(ctx @ Wctr^T + bc) ----------------
__global__ __launch_bounds__(256,2) void k_cheb3(
    const unsigned short* __restrict__ ctx, const unsigned short* __restrict__ Wctr,
    const float* __restrict__ bc, unsigned short* __restrict__ xg)
{
    __shared__ __align__(16) unsigned short A[128*104];   // 26.0 KB
    __shared__ __align__(16) unsigned short B[256*104];   // 52.0 KB
    const int bi = blockIdx.x;
    const int s = bi / NRB, rb = bi - s*NRB;
    ctx += (size_t)s*ROWS*CTXW;
    xg  += (size_t)s*ROWS*XGW;
    const int tid = threadIdx.x, wid = tid>>6, lane = tid&63;
    const int wm = wid>>1, wn = wid&1;
    const int r0 = rb*128;
    const int l15 = lane&15, lhi = lane>>4;

    #pragma unroll
    for (int i=0;i<6;i++){
        int idx = tid + i*256;            // 1536 chunks
        int row = idx/12, c = idx - row*12;
        *(int4*)&A[row*104 + c*8] = *(const int4*)&ctx[(size_t)(r0+row)*96 + c*8];
    }
    #pragma unroll
    for (int i=0;i<12;i++){
        int idx = tid + i*256;            // 3072 chunks
        int row = idx/12, c = idx - row*12;
        *(int4*)&B[row*104 + c*8] = *(const int4*)&Wctr[(size_t)row*96 + c*8];
    }
    __syncthreads();

    f32x4 acc[4][8] = {};
    #pragma unroll
    for (int ks=0; ks<3; ks++){
        bf16x8 a[4];
        #pragma unroll
        for (int mi=0;mi<4;mi++)
            a[mi] = *(const bf16x8*)&A[(wm*64+mi*16+l15)*104 + ks*32 + lhi*8];
        #pragma unroll
        for (int ni=0;ni<8;ni++){
            bf16x8 b = *(const bf16x8*)&B[(wn*128+ni*16+l15)*104 + ks*32 + lhi*8];
            #pragma unroll
            for (int mi=0;mi<4;mi++)
                acc[mi][ni] = __builtin_amdgcn_mfma_f32_16x16x32_bf16(a[mi], b, acc[mi][ni],0,0,0);
        }
    }
    #pragma unroll
    for (int ni=0;ni<8;ni++){
        int col = wn*128 + ni*16 + l15;
        float bcv = bc[col];
        #pragma unroll
        for (int mi=0;mi<4;mi++){
            #pragma unroll
            for (int v=0;v<4;v++){
                size_t row = r0 + wm*64 + mi*16 + lhi*4 + v;
                xg[row*XGW + 32 + col] = f2b(sigf(acc[mi][ni][v] + bcv));
            }
        }
    }
}

// ---------------- GRU tile compute (BK=64, swizzled 128B rows) ----------------
__device__ __forceinline__ void gtile64(const unsigned short* Ap, const unsigned short* Bp,
    int wm, int wn, int l15, int q0, int q1,
    f32x4 (&ar)[4][2], f32x4 (&az)[4][2], f32x4 (&a3)[4][2])
{
    bf16x8 a[4][2];
    #pragma unroll
    for (int mi=0;mi<4;mi++){
        int rb = (wm*64 + mi*16 + l15)*64;
        a[mi][0] = *(const bf16x8*)&Ap[rb + q0];
        a[mi][1] = *(const bf16x8*)&Ap[rb + q1];
    }
    #pragma unroll
    for (int slab=0; slab<3; slab++){
        bf16x8 b[2][2];
        #pragma unroll
        for (int ni=0; ni<2; ni++){
            int cb = (slab*64 + wn*32 + ni*16 + l15)*64;
            b[ni][0] = *(const bf16x8*)&Bp[cb + q0];
            b[ni][1] = *(const bf16x8*)&Bp[cb + q1];
        }
        f32x4 (&acc)[4][2] = (slab==0)?ar:((slab==1)?az:a3);
        #pragma unroll
        for (int kh=0; kh<2; kh++)
            #pragma unroll
            for (int mi=0; mi<4; mi++)
                #pragma unroll
                for (int ni=0; ni<2; ni++)
                    acc[mi][ni] = __builtin_amdgcn_mfma_f32_16x16x32_bf16(a[mi][kh], b[ni][kh], acc[mi][ni],0,0,0);
    }
}

// fused GRU cell: BK=64 dbuf gload_lds, XCD-aligned swizzled grid, optional fused FC (decoder)
__global__ __launch_bounds__(256,2) void k_gru4(
    const unsigned short* __restrict__ xg, const unsigned short* __restrict__ hbin,
    const unsigned short* __restrict__ Wihr, const unsigned short* __restrict__ Whhr,
    const float* __restrict__ bih, const float* __restrict__ bhh,
    unsigned short* __restrict__ hbout,
    const float* __restrict__ Wfc, float* __restrict__ outp, int p)
{
    __shared__ __align__(16) unsigned short As[2][128*64];   // 2 x 16 KB
    __shared__ __align__(16) unsigned short Bs[2][192*64];   // 2 x 24 KB
    // XCD-aligned bijective swizzle: the 4 col-blocks of row-block R share id%8
    const int bi = blockIdx.x;
    const int xc = bi & 7, t = bi >> 3;
    const int R = xc + 8*(t>>2);
    if (R >= NRB) return;
    const int r0 = R*128, j0 = (t&3)*64;

    const int tid = threadIdx.x, wid = tid>>6, lane = tid&63;
    const int wm = wid>>1, wn = wid&1;
    const int l15 = lane&15, lhi = lane>>4, x7 = l15&7;
    const int q0 = (lhi^x7)*8, q1 = q0^32;               // ushort offsets within 64-short row
    const int swz = ((lane&7)^(lane>>3))*16;             // byte chunk swizzle (chunk ^= row&7)
    const int lr = lane>>3;

    f32x4 ar[4][2]={}, az[4][2]={}, ain[4][2]={}, ahn[4][2]={};

    auto stageA = [&](int ks, int bs){
        char* Ld = (char*)&As[bs][0] + wid*4096;
        const char* src; size_t stride;
        if (ks < 5){ src = (const char*)xg   + (size_t)r0*640 + (size_t)ks*128     + (size_t)lr*640 + swz; stride = 640; }
        else       { src = (const char*)hbin + (size_t)r0*512 + (size_t)(ks-5)*128 + (size_t)lr*512 + swz; stride = 512; }
        #pragma unroll
        for (int i=0;i<4;i++)
            gload16(src + (size_t)(wid*32 + i*8)*stride, Ld + i*1024);
    };
    auto stageB = [&](int ks, int bs){
        const char* src; size_t stride; int kb;
        if (ks < 5){ src = (const char*)Wihr; stride = 640; kb = ks; }
        else       { src = (const char*)Whhr; stride = 512; kb = ks-5; }
        src += (size_t)kb*128 + (size_t)lr*stride + swz;
        #pragma unroll
        for (int i=0;i<6;i++){
            int j = wid*6 + i; int slab = j>>3; int c0 = (j&7)*8;
            gload16(src + (size_t)(slab*256 + j0 + c0)*stride, (char*)&Bs[bs][0] + j*1024);
        }
    };

    stageA(0,0); stageB(0,0);
    __syncthreads();
    for (int ks=0; ks<5; ks++){
        int cur = ks&1;
        { stageA(ks+1, cur^1); stageB(ks+1, cur^1); }
        gtile64(&As[cur][0], &Bs[cur][0], wm, wn, l15, q0, q1, ar, az, ain);
        __syncthreads();
    }
    for (int ks=5; ks<9; ks++){
        int cur = ks&1;
        if (ks<8){ stageA(ks+1, cur^1); stageB(ks+1, cur^1); }
        gtile64(&As[cur][0], &Bs[cur][0], wm, wn, l15, q0, q1, ar, az, ahn);
        __syncthreads();
    }
    // ---- fused gate epilogue (bf16 state) + optional fused FC partial ----
    float fcp[4][4] = {};
    float wf[2];
    if (p >= 0){
        wf[0] = Wfc[j0 + wn*32 + l15];
        wf[1] = Wfc[j0 + wn*32 + 16 + l15];
    }
    #pragma unroll
    for (int ni=0; ni<2; ni++){
        int col = j0 + wn*32 + ni*16 + l15;
        float br = bih[col]       + bhh[col];
        float bz = bih[col+HID]   + bhh[col+HID];
        float bi2 = bih[col+2*HID];
        float bh = bhh[col+2*HID];
        #pragma unroll
        for (int mi=0; mi<4; mi++){
            #pragma unroll
            for (int v=0; v<4; v++){
                size_t row = r0 + wm*64 + mi*16 + lhi*4 + v;
                float r  = sigf(ar[mi][ni][v] + br);
                float z  = sigf(az[mi][ni][v] + bz);
                float nn = tanhf(ain[mi][ni][v] + bi2 + r*(ahn[mi][ni][v] + bh));
                float ho = b2f(hbin[row*HID + col]);
                float hv = (1.f - z)*nn + z*ho;
                hbout[row*HID + col] = f2b(hv);
                if (p >= 0) fcp[mi][v] += hv * wf[ni];
            }
        }
    }
    if (p >= 0){
        #pragma unroll
        for (int mi=0; mi<4; mi++){
            #pragma unroll
            for (int v=0; v<4; v++){
                float s = fcp[mi][v];
                s += __shfl_xor(s, 1);
                s += __shfl_xor(s, 2);
                s += __shfl_xor(s, 4);
                s += __shfl_xor(s, 8);
                if (l15 == 0){
                    int row = r0 + wm*64 + mi*16 + lhi*4 + v;
                    int bb = row / NN, n = row - bb*NN;
                    atomicAdd(&outp[(size_t)(bb*PRED_L + p)*NN + n], s);
                }
            }
        }
    }
}

extern "C" void kernel_launch(void* const* d_in, const int* in_sizes, int n_in,
                              void* d_out, int out_size, void* d_ws, size_t ws_size,
                              hipStream_t stream){
    const float* x_hist = (const float*)d_in[0];
    const float* feats  = (const float*)d_in[1];
    const int*   ei     = (const int*)d_in[2];
    const float* Wc     = (const float*)d_in[3];
    const float* bc     = (const float*)d_in[4];
    const float* Wih    = (const float*)d_in[5];
    const float* bih    = (const float*)d_in[6];
    const float* Whh    = (const float*)d_in[7];
    const float* bhh    = (const float*)d_in[8];
    const float* Wfc    = (const float*)d_in[9];
    const float* bfc    = (const float*)d_in[10];
    float* out = (float*)d_out;

    char* wsp = (char*)d_ws;
    size_t off = 0;
    auto alloc = [&](size_t bytes)->char*{
        char* p = wsp + off; off = (off + bytes + 255) & ~(size_t)255; return p;
    };
    int*   deg  = (int*)  alloc(NN*4);
    int*   cnt  = (int*)  alloc(NN*4);
    int*   coff = (int*)  alloc((NN+1)*4);
    int*   csrc = (int*)  alloc(NE*4);
    float* cw   = (float*)alloc(NE*4);
    unsigned short* hbA = (unsigned short*)alloc((size_t)ROWS*HID*2);
    unsigned short* hbB = (unsigned short*)alloc((size_t)ROWS*HID*2);
    unsigned short* Wihr = (unsigned short*)alloc((size_t)768*XGW*2);
    unsigned short* Whhr = (unsigned short*)alloc((size_t)768*HID*2);
    unsigned short* Wctr = (unsigned short*)alloc((size_t)256*CTXW*2);

    // chunked batch buffers (encoder); CH chosen from ws_size, deterministic
    const size_t perSlice = (size_t)ROWS*INUM*4*2 + (size_t)ROWS*CTXW*2 + (size_t)ROWS*XGW*2 + 4*256;
    int CH = 1;
    for (int c : {8,6,4,2}){
        if (off + (size_t)c*perSlice + (1<<20) <= ws_size){ CH = c; break; }
    }
    float* xt_b = (float*)alloc((size_t)CH*ROWS*INUM*4);
    float* T1_b = (float*)alloc((size_t)CH*ROWS*INUM*4);
    unsigned short* ctx_b = (unsigned short*)alloc((size_t)CH*ROWS*CTXW*2);
    unsigned short* xg_b  = (unsigned short*)alloc((size_t)CH*ROWS*XGW*2);

    hipMemsetAsync(deg, 0, NN*4, stream);
    hipMemsetAsync(cnt, 0, NN*4, stream);
    hipMemsetAsync(hbA, 0, (size_t)ROWS*HID*2, stream);
    hipMemsetAsync(xg_b, 0, (size_t)CH*ROWS*XGW*2, stream);  // zero pad cols persist
    hipMemsetAsync(out, 0, (size_t)out_size*4, stream);      // fc atomics accumulate into out

    k_count<<<(NE+255)/256,256,0,stream>>>(ei, deg, cnt);
    k_prefix<<<1,64,0,stream>>>(cnt, coff);
    k_fillw<<<NRB,256,0,stream>>>(ei, deg, coff, csrc, cw);

    { int n = 768*XGW; k_wihr<<<(n+255)/256,256,0,stream>>>(Wih, Wihr); }
    { int n = 768*HID; k_f2b<<<(n+255)/256,256,0,stream>>>(Whh, Whhr, n); }
    { int n = 256*CTXW; k_wctr<<<(n+255)/256,256,0,stream>>>(Wc, Wctr); }

    unsigned short* hbin = hbA; unsigned short* hbout = hbB;
    const int gruGrid = 1504;     // 8 XCD classes; (R,c) swizzled in-kernel
    const int NT  = (ROWS*INUM+255)/256;
    const int NT8 = (ROWS*8+255)/256;

    // ---- encoder: batch the h-independent chain in chunks of CH steps ----
    for (int t0=0; t0<HIST_L-1; t0+=CH){
        int nc = HIST_L-1-t0; if (nc > CH) nc = CH;
        dim3 gb(NT, nc), gl(NT8, nc);
        k_build<<<gb,256,0,stream>>>(x_hist, HIST_L*NN, t0*NN, NN, 0, bfc, feats, t0+1, xt_b, ctx_b, xg_b);
        k_lx4<<<gl,256,0,stream>>>(xt_b, coff, csrc, cw, nullptr, 1.f, T1_b, ctx_b + 32);
        k_lx4<<<gl,256,0,stream>>>(T1_b, coff, csrc, cw, xt_b, 2.f, nullptr, ctx_b + 64);
        k_cheb3<<<NRB*nc,256,0,stream>>>(ctx_b, Wctr, bc, xg_b);
        for (int s=0; s<nc; s++){
            k_gru4<<<gruGrid,256,0,stream>>>(xg_b + (size_t)s*ROWS*XGW, hbin, Wihr, Whhr, bih, bhh, hbout, Wfc, out, -1);
            unsigned short* tmp = hbin; hbin = hbout; hbout = tmp;
        }
    }
    // ---- decoder: sequential, slice 0 of batch buffers ----
    for (int p=0;p<PRED_L;p++){
        dim3 gb(NT,1), gl(NT8,1);
        if (p==0) k_build<<<gb,256,0,stream>>>(x_hist, HIST_L*NN, (HIST_L-1)*NN, 0, 0, bfc, feats, HIST_L+p, xt_b, ctx_b, xg_b);
        else      k_build<<<gb,256,0,stream>>>(out, PRED_L*NN, (p-1)*NN, 0, 1, bfc, feats, HIST_L+p, xt_b, ctx_b, xg_b);
        k_lx4<<<gl,256,0,stream>>>(xt_b, coff, csrc, cw, nullptr, 1.f, T1_b, ctx_b + 32);
        k_lx4<<<gl,256,0,stream>>>(T1_b, coff, csrc, cw, xt_b, 2.f, nullptr, ctx_b + 64);
        k_cheb3<<<NRB,256,0,stream>>>(ctx_b, Wctr, bc, xg_b);
        k_gru4<<<gruGrid,256,0,stream>>>(xg_b, hbin, Wihr, Whhr, bih, bhh, hbout, Wfc, out, p);
        unsigned short* tmp = hbin; hbin = hbout; hbout = tmp;
    }
}